// Round 14
// baseline (2180.896 us; speedup 1.0000x reference)
//
#include <hip/hip_runtime.h>
#include <stdint.h>

#define BATCH 4
#define NPTS  8192
#define CFEAT 64
#define MCENT 2048
#define NCENT (BATCH * MCENT)
#define KMAX  64
#define NEGV  -1e30f
#define KNN_CAP 320
#define PROG_STRIDE 32   // ints; one 128B cache line per batch counter

// Exact-rounding squared distance, matching numpy's ((dx*dx+dy*dy)+dz*dz)
// with NO fma contraction (discrete neighbor selection requires bit parity).
__device__ __forceinline__ float dist2(float ax, float ay, float az,
                                       float bx, float by, float bz) {
    float dx = __fsub_rn(ax, bx);
    float dy = __fsub_rn(ay, by);
    float dz = __fsub_rn(az, bz);
    return __fadd_rn(__fadd_rn(__fmul_rn(dx, dx), __fmul_rn(dy, dy)),
                     __fmul_rn(dz, dz));
}

template <int CTRL>
__device__ __forceinline__ int dppi(int v) {
    return __builtin_amdgcn_update_dpp(v, v, CTRL, 0xF, 0xF, false);
}

// u64 max-combine with a DPP lane permute (lo/hi words permuted separately).
#define KSTEP(k, C_) { int klo_ = dppi<C_>((int)(unsigned int)(k));           \
                       int khi_ = dppi<C_>((int)(unsigned int)((k) >> 32));   \
                       unsigned long long ok_ =                               \
                           ((unsigned long long)(unsigned int)khi_ << 32) |   \
                           (unsigned int)klo_;                                \
                       (k) = ok_ > (k) ? ok_ : (k); }

// ---------------------------------------------------------------------------
// LDS union: producer (FPS) and consumer blocks use disjoint layouts.
// 96.1 KB -> 1 block/CU; 256 threads = 1 wave/SIMD -> 256-VGPR budget
// (r7/r8 spill fix, confirmed r10: VGPR 132, WRITE 2.67GB -> 12MB).
// ---------------------------------------------------------------------------
struct FpsLds {
    float2 sxy[NPTS];                    // 64 KB
    float  sz[NPTS];                     // 32 KB
    unsigned long long skey[2][4];
};
struct KnnLds {
    float4 p3[KMAX];                     // pos[nbr]-ctr (w=0)
    float  H[KMAX * 128];                // 32 KB hidden activations
    unsigned long long cand[KNN_CAP];    // 2.5 KB
    float  pm2[4][256];                  // 4 KB  (C2==256 combine)
    float  pm[256];                      // 1 KB  (C2==128 combine)
    int    hist[64];
    int    nbr[KMAX];
    float  nd2s[KMAX];
    float  ctr[4];
    int    B64, total, cnt2, cntk;
};
union MegaLds { FpsLds f; KnnLds k; };

// ---------------------------------------------------------------------------
// Per-centroid MLP phase, 256 threads (r6 structure; per-(k,j) fma order
// bit-exact: bias, rows 0..67 / i=0..C1-1 ascending). Unchanged from r11.
// ---------------------------------------------------------------------------
template <int K, int C1, int C2, int OUTOFF>
__device__ __forceinline__ void mlp_phase(
        KnnLds& L, const float* __restrict__ x,
        const float* __restrict__ W1, const float* __restrict__ B1,
        const float* __restrict__ W2, const float* __restrict__ B2,
        float* __restrict__ out, float r2, int c, int b, int t) {
    constexpr int HK  = K / 8;      // k-rows per half-wave (8 half-waves)
    constexpr int NJ1 = C1 / 32;    // j-cols per lane (4 or 2)
    {
        const int hw = t >> 5;          // half-wave 0..7
        const int sl = t & 31;
        const int k0 = hw * HK;
        const int j0 = sl * NJ1;

        int xo[HK];
#pragma unroll
        for (int kk = 0; kk < HK; ++kk)
            xo[kk] = (b * NPTS + L.nbr[k0 + kk]) * CFEAT;

        float acc[HK][NJ1];
#pragma unroll
        for (int kk = 0; kk < HK; ++kk)
#pragma unroll
            for (int j = 0; j < NJ1; ++j) acc[kk][j] = B1[j0 + j];

#pragma unroll 4
        for (int q = 0; q < 16; ++q) {  // x rows 4q..4q+3
            float wr[4][NJ1];
#pragma unroll
            for (int r = 0; r < 4; ++r)
#pragma unroll
                for (int j = 0; j < NJ1; ++j)
                    wr[r][j] = W1[(4 * q + r) * C1 + j0 + j];
#pragma unroll
            for (int kk = 0; kk < HK; ++kk) {
                float4 h = *(const float4*)(x + xo[kk] + 4 * q);
#pragma unroll
                for (int j = 0; j < NJ1; ++j) {
                    float a = acc[kk][j];
                    a = fmaf(h.x, wr[0][j], a);
                    a = fmaf(h.y, wr[1][j], a);
                    a = fmaf(h.z, wr[2][j], a);
                    a = fmaf(h.w, wr[3][j], a);
                    acc[kk][j] = a;
                }
            }
        }
        {   // tail: rows 64,65,66 (pos-delta) + zero row 67
            float wr[4][NJ1];
#pragma unroll
            for (int r = 0; r < 3; ++r)
#pragma unroll
                for (int j = 0; j < NJ1; ++j)
                    wr[r][j] = W1[(64 + r) * C1 + j0 + j];
#pragma unroll
            for (int j = 0; j < NJ1; ++j) wr[3][j] = 0.f;
#pragma unroll
            for (int kk = 0; kk < HK; ++kk) {
                float4 h = L.p3[k0 + kk];       // h.w == 0
#pragma unroll
                for (int j = 0; j < NJ1; ++j) {
                    float a = acc[kk][j];
                    a = fmaf(h.x, wr[0][j], a);
                    a = fmaf(h.y, wr[1][j], a);
                    a = fmaf(h.z, wr[2][j], a);
                    a = fmaf(h.w, wr[3][j], a);
                    acc[kk][j] = a;
                }
            }
        }
#pragma unroll
        for (int kk = 0; kk < HK; ++kk) {
            if constexpr (NJ1 == 4) {
                float4 o;
                o.x = fmaxf(acc[kk][0], 0.f); o.y = fmaxf(acc[kk][1], 0.f);
                o.z = fmaxf(acc[kk][2], 0.f); o.w = fmaxf(acc[kk][3], 0.f);
                *(float4*)&L.H[(k0 + kk) * C1 + j0] = o;
            } else {
                float2 o;
                o.x = fmaxf(acc[kk][0], 0.f); o.y = fmaxf(acc[kk][1], 0.f);
                *(float2*)&L.H[(k0 + kk) * C1 + j0] = o;
            }
        }
    }
    __syncthreads();

    const int cntk = L.cntk;
    const int cntp = cntk < K ? cntk : K;

    if constexpr (C2 == 256) {
        // k-split across 4 waves; 4 j columns per lane; acc in registers.
        const int lane_ = t & 63;
        const int wv_   = t >> 6;           // 0..3
        const int j0    = lane_ * 4;
        const int k0    = wv_ * (K / 4);    // 16 k-rows per wave
        float4 bjv = *(const float4*)&B2[j0];
        float acc[K / 4][4];
#pragma unroll
        for (int kk = 0; kk < K / 4; ++kk) {
            acc[kk][0] = bjv.x; acc[kk][1] = bjv.y;
            acc[kk][2] = bjv.z; acc[kk][3] = bjv.w;
        }
        for (int i = 0; i < C1; i += 4) {
            float4 w0 = *(const float4*)&W2[(i + 0) * C2 + j0];
            float4 w1 = *(const float4*)&W2[(i + 1) * C2 + j0];
            float4 w2 = *(const float4*)&W2[(i + 2) * C2 + j0];
            float4 w3 = *(const float4*)&W2[(i + 3) * C2 + j0];
#pragma unroll
            for (int kk = 0; kk < K / 4; ++kk) {
                float4 h = *(const float4*)&L.H[(k0 + kk) * C1 + i];  // bcast
                acc[kk][0] = fmaf(h.x, w0.x, acc[kk][0]);
                acc[kk][0] = fmaf(h.y, w1.x, acc[kk][0]);
                acc[kk][0] = fmaf(h.z, w2.x, acc[kk][0]);
                acc[kk][0] = fmaf(h.w, w3.x, acc[kk][0]);
                acc[kk][1] = fmaf(h.x, w0.y, acc[kk][1]);
                acc[kk][1] = fmaf(h.y, w1.y, acc[kk][1]);
                acc[kk][1] = fmaf(h.z, w2.y, acc[kk][1]);
                acc[kk][1] = fmaf(h.w, w3.y, acc[kk][1]);
                acc[kk][2] = fmaf(h.x, w0.z, acc[kk][2]);
                acc[kk][2] = fmaf(h.y, w1.z, acc[kk][2]);
                acc[kk][2] = fmaf(h.z, w2.z, acc[kk][2]);
                acc[kk][2] = fmaf(h.w, w3.z, acc[kk][2]);
                acc[kk][3] = fmaf(h.x, w0.w, acc[kk][3]);
                acc[kk][3] = fmaf(h.y, w1.w, acc[kk][3]);
                acc[kk][3] = fmaf(h.z, w2.w, acc[kk][3]);
                acc[kk][3] = fmaf(h.w, w3.w, acc[kk][3]);
            }
        }
        float m0 = NEGV, m1 = NEGV, m2 = NEGV, m3 = NEGV;
#pragma unroll
        for (int kk = 0; kk < K / 4; ++kk) {
            bool v = (k0 + kk < cntp) && (L.nd2s[k0 + kk] <= r2);
            if (v) {                            // wave-uniform branch
                m0 = fmaxf(m0, fmaxf(acc[kk][0], 0.f));
                m1 = fmaxf(m1, fmaxf(acc[kk][1], 0.f));
                m2 = fmaxf(m2, fmaxf(acc[kk][2], 0.f));
                m3 = fmaxf(m3, fmaxf(acc[kk][3], 0.f));
            }
        }
        float4 mv; mv.x = m0; mv.y = m1; mv.z = m2; mv.w = m3;
        *(float4*)&L.pm2[wv_][j0] = mv;
        __syncthreads();
        float r = fmaxf(fmaxf(L.pm2[0][t], L.pm2[1][t]),
                        fmaxf(L.pm2[2][t], L.pm2[3][t]));
        out[c * 384 + OUTOFF + t] = r;
    } else {
        // C2 == 128: 2 thread-groups split the k range, combine via LDS
        const int j2 = t % C2;
        const int g  = t / C2;
        float w2c[C1];
#pragma unroll
        for (int i = 0; i < C1; ++i) w2c[i] = W2[i * C2 + j2];
        const float bj = B2[j2];
        float omax = NEGV;
        for (int k = g; k < K; k += 2) {
            bool v = (k < cntp) && (L.nd2s[k] <= r2);
            if (!v) continue;
            float acc = bj;
            const float4* hr = (const float4*)&L.H[k * C1];
#pragma unroll
            for (int q = 0; q < C1 / 4; ++q) {
                float4 h = hr[q];
                acc = fmaf(h.x, w2c[4 * q + 0], acc);
                acc = fmaf(h.y, w2c[4 * q + 1], acc);
                acc = fmaf(h.z, w2c[4 * q + 2], acc);
                acc = fmaf(h.w, w2c[4 * q + 3], acc);
            }
            omax = fmaxf(omax, fmaxf(acc, 0.f));
        }
        L.pm[t] = omax;
        __syncthreads();
        if (t < C2) out[c * 384 + OUTOFF + t] = fmaxf(L.pm[t], L.pm[t + C2]);
    }
}

// ---------------------------------------------------------------------------
// Fused mega-kernel, 256 threads/block, batch-interleaved consumers.
// r14 changes (interference attack — r12's publish levers were neutral):
//  1. prog[] padded to ONE CACHE LINE PER BATCH (stride 128B). Previously
//     all 4 counters shared one line; ~252 resident consumer-t0s polled it
//     with agent-scope atomic loads every ~0.2us (~1260 line-accesses/us),
//     and the producer's RELEASE had to win exclusive access against that
//     storm — the suspected ~250us producer slowdown vs standalone.
//  2. Poll grain s_sleep(8) -> s_sleep(32) (~0.85us): per-line access rate
//     drops to ~74/us. Wake latency +1us << 64-iter publish granularity.
//     Poll cap 2^18 (worst case ~0.2s; pathology = visible fail, not hang).
// Protocol semantics unchanged (same release/poll pattern, passed 4x).
// ---------------------------------------------------------------------------
#define FPS_T   256
#define FPS_W   (FPS_T / 64)

#define REP32(X) X(0) X(1) X(2) X(3) X(4) X(5) X(6) X(7) \
                 X(8) X(9) X(10) X(11) X(12) X(13) X(14) X(15) \
                 X(16) X(17) X(18) X(19) X(20) X(21) X(22) X(23) \
                 X(24) X(25) X(26) X(27) X(28) X(29) X(30) X(31)

__global__ __launch_bounds__(256, 1) void mega_kernel(
        const float* __restrict__ x, const float* __restrict__ pos,
        const float* __restrict__ w1_0, const float* __restrict__ b1_0,
        const float* __restrict__ w1_1, const float* __restrict__ b1_1,
        const float* __restrict__ w2_0, const float* __restrict__ b2_0,
        const float* __restrict__ w2_1, const float* __restrict__ b2_1,
        float* __restrict__ out, float* pos_s, int* prog) {
    const int t = threadIdx.x;
    __shared__ MegaLds U;

    if (blockIdx.x < BATCH) {
        // =================== FPS producer ===================
        const int b = blockIdx.x;
        const float* pb = pos + b * NPTS * 3;
        const int w = t >> 6;               // wave 0..3
        const int lane = t & 63;

#define FPS_DECL(i) float px##i, py##i, pz##i, mind##i;
        REP32(FPS_DECL)
#undef FPS_DECL

#define FPS_LOAD(i) { int p = (i << 8) + t;                                   \
                      px##i = pb[3 * p + 0];                                  \
                      py##i = pb[3 * p + 1];                                  \
                      pz##i = pb[3 * p + 2];                                  \
                      float2 xy_; xy_.x = px##i; xy_.y = py##i;               \
                      U.f.sxy[p] = xy_;  U.f.sz[p] = pz##i;                   \
                      mind##i = 1e30f;                                        \
                      asm volatile("" : "+v"(px##i), "+v"(py##i), "+v"(pz##i)); }
        REP32(FPS_LOAD)
#undef FPS_LOAD
        __syncthreads();

        float lx = U.f.sxy[0].x, ly = U.f.sxy[0].y, lz = U.f.sz[0];

        for (int m = 0; m < MCENT - 1; ++m) {
            if (t == 0) {
                float* o = pos_s + (b * MCENT + m) * 3;   // plain stores
                o[0] = lx; o[1] = ly; o[2] = lz;
                if ((m & 63) == 63)
                    __hip_atomic_store(&prog[b * PROG_STRIDE], m + 1,
                                       __ATOMIC_RELEASE,
                                       __HIP_MEMORY_SCOPE_AGENT);
            }

            // update mind (32 independent ops, full ILP)
#define FPS_UPD(i) { float d = dist2(px##i, py##i, pz##i, lx, ly, lz);        \
                     mind##i = fminf(mind##i, d); }
            REP32(FPS_UPD)
#undef FPS_UPD

            // tournament-tree argmax over 32 slots (strict >, left bias)
#define CMB(vo, io, va, ia, vb, ib)                                           \
            float vo; int io; { bool tk_ = (vb) > (va);                       \
                                vo = tk_ ? (vb) : (va);                       \
                                io = tk_ ? (ib) : (ia); }
            CMB(A0v,A0i,  mind0,0,   mind1,1)   CMB(A1v,A1i,  mind2,2,   mind3,3)
            CMB(A2v,A2i,  mind4,4,   mind5,5)   CMB(A3v,A3i,  mind6,6,   mind7,7)
            CMB(A4v,A4i,  mind8,8,   mind9,9)   CMB(A5v,A5i,  mind10,10, mind11,11)
            CMB(A6v,A6i,  mind12,12, mind13,13) CMB(A7v,A7i,  mind14,14, mind15,15)
            CMB(A8v,A8i,  mind16,16, mind17,17) CMB(A9v,A9i,  mind18,18, mind19,19)
            CMB(A10v,A10i,mind20,20, mind21,21) CMB(A11v,A11i,mind22,22, mind23,23)
            CMB(A12v,A12i,mind24,24, mind25,25) CMB(A13v,A13i,mind26,26, mind27,27)
            CMB(A14v,A14i,mind28,28, mind29,29) CMB(A15v,A15i,mind30,30, mind31,31)
            CMB(B0v,B0i, A0v,A0i,  A1v,A1i)   CMB(B1v,B1i, A2v,A2i,  A3v,A3i)
            CMB(B2v,B2i, A4v,A4i,  A5v,A5i)   CMB(B3v,B3i, A6v,A6i,  A7v,A7i)
            CMB(B4v,B4i, A8v,A8i,  A9v,A9i)   CMB(B5v,B5i, A10v,A10i,A11v,A11i)
            CMB(B6v,B6i, A12v,A12i,A13v,A13i) CMB(B7v,B7i, A14v,A14i,A15v,A15i)
            CMB(C0v,C0i, B0v,B0i, B1v,B1i)    CMB(C1v,C1i, B2v,B2i, B3v,B3i)
            CMB(C2v,C2i, B4v,B4i, B5v,B5i)    CMB(C3v,C3i, B6v,B6i, B7v,B7i)
            CMB(D0v,D0i, C0v,C0i, C1v,C1i)    CMB(D1v,D1i, C2v,C2i, C3v,C3i)
            CMB(E0v,E0i, D0v,D0i, D1v,D1i)
#undef CMB
            const float bv = E0v;
            const int   bp = (E0i << 8) + t;    // global point index

            // single u64 key chain: (d2 bits << 13) | (8191 - idx); 6
            // dependent KSTEPs absorb to lane 63 (value-monotone, inv-idx
            // tie -> min global index; r3-validated bit-exact).
            unsigned long long key =
                ((unsigned long long)__float_as_uint(bv) << 13) |
                (unsigned int)(8191 - bp);
            KSTEP(key, 0xB1)    // quad_perm xor1
            KSTEP(key, 0x4E)    // quad_perm xor2
            KSTEP(key, 0x141)   // row_half_mirror
            KSTEP(key, 0x140)   // row_mirror
            KSTEP(key, 0x142)   // row_bcast15
            KSTEP(key, 0x143)   // row_bcast31 -> lane63 holds wave winner

            const int par = m & 1;
            if (lane == 63) U.f.skey[par][w] = key;
            __syncthreads();

            // cross-wave: 4 slots, 2-step u64 butterfly (all-reduce)
            unsigned long long k = U.f.skey[par][t & 3];
            KSTEP(k, 0xB1)
            KSTEP(k, 0x4E)

            int gp = 8191 - (int)(k & 0x1FFFULL);
            float2 cxy = U.f.sxy[gp];           // broadcast LDS read
            lx = cxy.x; ly = cxy.y; lz = U.f.sz[gp];
        }
        if (t == 0) {
            float* o = pos_s + (b * MCENT + MCENT - 1) * 3;
            o[0] = lx; o[1] = ly; o[2] = lz;
            __hip_atomic_store(&prog[b * PROG_STRIDE], MCENT,
                               __ATOMIC_RELEASE, __HIP_MEMORY_SCOPE_AGENT);
        }
        return;
    }

    // =================== per-centroid consumer (batch-interleaved) =========
    const int idx = blockIdx.x - BATCH;
    const int b   = idx & 3;            // batches alternate in dispatch order
    const int m   = idx >> 2;
    const int c   = b * MCENT + m;
    KnnLds& L = U.k;
    const float* pb = pos + b * NPTS * 3;

    if (t < KMAX) { L.nbr[t] = 0; L.nd2s[t] = 1e30f; L.hist[t] = 0; }
    if (t == 0) L.cnt2 = 0;

    if (t == 0) {
        int tries = 0;
        while (__hip_atomic_load(&prog[b * PROG_STRIDE], __ATOMIC_RELAXED,
                                 __HIP_MEMORY_SCOPE_AGENT) < m + 1) {
            __builtin_amdgcn_s_sleep(32);
            if (++tries >= (1 << 18)) break;    // pathology -> visible fail
        }
        asm volatile("" ::: "memory");
        // centroid coords via LLC atomic loads (released by producer)
        L.ctr[0] = __hip_atomic_load(&pos_s[c * 3 + 0], __ATOMIC_RELAXED,
                                     __HIP_MEMORY_SCOPE_AGENT);
        L.ctr[1] = __hip_atomic_load(&pos_s[c * 3 + 1], __ATOMIC_RELAXED,
                                     __HIP_MEMORY_SCOPE_AGENT);
        L.ctr[2] = __hip_atomic_load(&pos_s[c * 3 + 2], __ATOMIC_RELAXED,
                                     __HIP_MEMORY_SCOPE_AGENT);
    }
    __syncthreads();
    const float cx = L.ctr[0], cy = L.ctr[1], cz = L.ctr[2];

    // ---- knn: histogram radix-select + exact rank (r6 256t) ----
    float d2r[32];
#pragma unroll
    for (int i = 0; i < 32; ++i) {
        int p = (i << 8) + t;
        float d2 = dist2(cx, cy, cz, pb[3 * p + 0], pb[3 * p + 1], pb[3 * p + 2]);
        d2r[i] = d2;
        if (d2 <= 0.16f) {
            int bkt = (int)(d2 * 400.0f);      // monotone; 0.16f*400 < 64
            bkt = bkt > 63 ? 63 : bkt;
            atomicAdd(&L.hist[bkt], 1);
        }
    }
    __syncthreads();
    if (t == 0) {
        int cum = 0, B = -1;
#pragma unroll
        for (int j = 0; j < 64; ++j) {
            cum += L.hist[j];
            if (B < 0 && cum >= 64) B = j;
        }
        L.B64 = (B < 0) ? 63 : B;
        L.total = cum;
    }
    __syncthreads();
    const int B64 = L.B64;
#pragma unroll
    for (int i = 0; i < 32; ++i) {
        float d2 = d2r[i];
        if (d2 <= 0.16f) {
            int bkt = (int)(d2 * 400.0f);
            bkt = bkt > 63 ? 63 : bkt;
            if (bkt <= B64) {
                int slot = atomicAdd(&L.cnt2, 1);
                if (slot < KNN_CAP) {
                    int p = (i << 8) + t;
                    L.cand[slot] =
                        ((unsigned long long)__float_as_uint(d2) << 32) |
                        (unsigned int)p;
                }
            }
        }
    }
    __syncthreads();
    const int C = L.cnt2 < KNN_CAP ? L.cnt2 : KNN_CAP;
    for (int tc = t; tc < C; tc += 256) {
        unsigned long long my = L.cand[tc];
        int rank = 0;
        for (int j = 0; j < C; ++j) rank += (L.cand[j] < my) ? 1 : 0;
        if (rank < KMAX) {
            L.nbr[rank]  = (int)(my & 0xffffffffULL);
            L.nd2s[rank] = __uint_as_float((unsigned int)(my >> 32));
        }
    }
    if (t == 0) L.cntk = L.total < KMAX ? L.total : KMAX;
    __syncthreads();
    if (t < KMAX) {
        const float* pp = pos + (b * NPTS + L.nbr[t]) * 3;
        float4 p;
        p.x = pp[0] - cx; p.y = pp[1] - cy; p.z = pp[2] - cz; p.w = 0.f;
        L.p3[t] = p;
    }
    __syncthreads();

    mlp_phase<32, 64, 128, 0>(L, x, w1_0, b1_0, w1_1, b1_1, out, 0.04f, c, b, t);
    __syncthreads();
    mlp_phase<64, 128, 256, 128>(L, x, w2_0, b2_0, w2_1, b2_1, out, 0.16f, c, b, t);
}
#undef KSTEP

extern "C" void kernel_launch(void* const* d_in, const int* in_sizes, int n_in,
                              void* d_out, int out_size, void* d_ws, size_t ws_size,
                              hipStream_t stream) {
    const float* x    = (const float*)d_in[0];
    const float* pos  = (const float*)d_in[1];
    const float* w1_0 = (const float*)d_in[2];
    const float* b1_0 = (const float*)d_in[3];
    const float* w1_1 = (const float*)d_in[4];
    const float* b1_1 = (const float*)d_in[5];
    const float* w2_0 = (const float*)d_in[6];
    const float* b2_0 = (const float*)d_in[7];
    const float* w2_1 = (const float*)d_in[8];
    const float* b2_1 = (const float*)d_in[9];

    float* out   = (float*)d_out;
    float* pos_s = out + NCENT * 384;          // second output

    int* prog = (int*)d_ws;                    // 4 counters, 128B apart

    hipMemsetAsync(prog, 0, BATCH * PROG_STRIDE * sizeof(int), stream);
    mega_kernel<<<BATCH + NCENT, 256, 0, stream>>>(
        x, pos, w1_0, b1_0, w1_1, b1_1, w2_0, b2_0, w2_1, b2_1,
        out, pos_s, prog);
}

// Round 16
// 2166.239 us; speedup vs baseline: 1.0068x; 1.0068x over previous
//
#include <hip/hip_runtime.h>
#include <stdint.h>

#define BATCH 4
#define NPTS  8192
#define CFEAT 64
#define MCENT 2048
#define NCENT (BATCH * MCENT)
#define KMAX  64
#define NEGV  -1e30f
#define KNN_CAP 320
#define PROG_STRIDE 32   // ints; one 128B cache line per batch counter

// Exact-rounding squared distance, matching numpy's ((dx*dx+dy*dy)+dz*dz)
// with NO fma contraction (discrete neighbor selection requires bit parity).
__device__ __forceinline__ float dist2(float ax, float ay, float az,
                                       float bx, float by, float bz) {
    float dx = __fsub_rn(ax, bx);
    float dy = __fsub_rn(ay, by);
    float dz = __fsub_rn(az, bz);
    return __fadd_rn(__fadd_rn(__fmul_rn(dx, dx), __fmul_rn(dy, dy)),
                     __fmul_rn(dz, dz));
}

template <int CTRL>
__device__ __forceinline__ int dppi(int v) {
    return __builtin_amdgcn_update_dpp(v, v, CTRL, 0xF, 0xF, false);
}

// u64 max-combine with a DPP lane permute (lo/hi words permuted separately).
#define KSTEP(k, C_) { int klo_ = dppi<C_>((int)(unsigned int)(k));           \
                       int khi_ = dppi<C_>((int)(unsigned int)((k) >> 32));   \
                       unsigned long long ok_ =                               \
                           ((unsigned long long)(unsigned int)khi_ << 32) |   \
                           (unsigned int)klo_;                                \
                       (k) = ok_ > (k) ? ok_ : (k); }

// ---------------------------------------------------------------------------
// LDS union: producer (FPS) and consumer blocks use disjoint layouts.
// 104.1 KB -> 1 block/CU; 256 threads = 1 wave/SIMD -> 256-VGPR budget.
// ---------------------------------------------------------------------------
struct FpsLds {
    float2 sxy[NPTS];                    // 64 KB
    float  sz[NPTS];                     // 32 KB
    int    s_win[MCENT];                 // 8 KB winner indices (t0-only)
    unsigned long long skey[2][4];
};
struct KnnLds {
    float4 p3[KMAX];                     // pos[nbr]-ctr (w=0)
    float  H[KMAX * 128];                // 32 KB hidden activations
    unsigned long long cand[KNN_CAP];    // 2.5 KB
    float  pm2[4][256];                  // 4 KB  (C2==256 combine)
    float  pm[256];                      // 1 KB  (C2==128 combine)
    int    hist[64];
    int    nbr[KMAX];
    float  nd2s[KMAX];
    float  ctr[4];
    int    B64, total, cnt2, cntk;
};
union MegaLds { FpsLds f; KnnLds k; };

// ---------------------------------------------------------------------------
// Per-centroid MLP phase, 256 threads (r6 structure; per-(k,j) fma order
// bit-exact: bias, rows 0..67 / i=0..C1-1 ascending). Unchanged from r11.
// ---------------------------------------------------------------------------
template <int K, int C1, int C2, int OUTOFF>
__device__ __forceinline__ void mlp_phase(
        KnnLds& L, const float* __restrict__ x,
        const float* __restrict__ W1, const float* __restrict__ B1,
        const float* __restrict__ W2, const float* __restrict__ B2,
        float* __restrict__ out, float r2, int c, int b, int t) {
    constexpr int HK  = K / 8;      // k-rows per half-wave (8 half-waves)
    constexpr int NJ1 = C1 / 32;    // j-cols per lane (4 or 2)
    {
        const int hw = t >> 5;          // half-wave 0..7
        const int sl = t & 31;
        const int k0 = hw * HK;
        const int j0 = sl * NJ1;

        int xo[HK];
#pragma unroll
        for (int kk = 0; kk < HK; ++kk)
            xo[kk] = (b * NPTS + L.nbr[k0 + kk]) * CFEAT;

        float acc[HK][NJ1];
#pragma unroll
        for (int kk = 0; kk < HK; ++kk)
#pragma unroll
            for (int j = 0; j < NJ1; ++j) acc[kk][j] = B1[j0 + j];

#pragma unroll 4
        for (int q = 0; q < 16; ++q) {  // x rows 4q..4q+3
            float wr[4][NJ1];
#pragma unroll
            for (int r = 0; r < 4; ++r)
#pragma unroll
                for (int j = 0; j < NJ1; ++j)
                    wr[r][j] = W1[(4 * q + r) * C1 + j0 + j];
#pragma unroll
            for (int kk = 0; kk < HK; ++kk) {
                float4 h = *(const float4*)(x + xo[kk] + 4 * q);
#pragma unroll
                for (int j = 0; j < NJ1; ++j) {
                    float a = acc[kk][j];
                    a = fmaf(h.x, wr[0][j], a);
                    a = fmaf(h.y, wr[1][j], a);
                    a = fmaf(h.z, wr[2][j], a);
                    a = fmaf(h.w, wr[3][j], a);
                    acc[kk][j] = a;
                }
            }
        }
        {   // tail: rows 64,65,66 (pos-delta) + zero row 67
            float wr[4][NJ1];
#pragma unroll
            for (int r = 0; r < 3; ++r)
#pragma unroll
                for (int j = 0; j < NJ1; ++j)
                    wr[r][j] = W1[(64 + r) * C1 + j0 + j];
#pragma unroll
            for (int j = 0; j < NJ1; ++j) wr[3][j] = 0.f;
#pragma unroll
            for (int kk = 0; kk < HK; ++kk) {
                float4 h = L.p3[k0 + kk];       // h.w == 0
#pragma unroll
                for (int j = 0; j < NJ1; ++j) {
                    float a = acc[kk][j];
                    a = fmaf(h.x, wr[0][j], a);
                    a = fmaf(h.y, wr[1][j], a);
                    a = fmaf(h.z, wr[2][j], a);
                    a = fmaf(h.w, wr[3][j], a);
                    acc[kk][j] = a;
                }
            }
        }
#pragma unroll
        for (int kk = 0; kk < HK; ++kk) {
            if constexpr (NJ1 == 4) {
                float4 o;
                o.x = fmaxf(acc[kk][0], 0.f); o.y = fmaxf(acc[kk][1], 0.f);
                o.z = fmaxf(acc[kk][2], 0.f); o.w = fmaxf(acc[kk][3], 0.f);
                *(float4*)&L.H[(k0 + kk) * C1 + j0] = o;
            } else {
                float2 o;
                o.x = fmaxf(acc[kk][0], 0.f); o.y = fmaxf(acc[kk][1], 0.f);
                *(float2*)&L.H[(k0 + kk) * C1 + j0] = o;
            }
        }
    }
    __syncthreads();

    const int cntk = L.cntk;
    const int cntp = cntk < K ? cntk : K;

    if constexpr (C2 == 256) {
        // k-split across 4 waves; 4 j columns per lane; acc in registers.
        const int lane_ = t & 63;
        const int wv_   = t >> 6;           // 0..3
        const int j0    = lane_ * 4;
        const int k0    = wv_ * (K / 4);    // 16 k-rows per wave
        float4 bjv = *(const float4*)&B2[j0];
        float acc[K / 4][4];
#pragma unroll
        for (int kk = 0; kk < K / 4; ++kk) {
            acc[kk][0] = bjv.x; acc[kk][1] = bjv.y;
            acc[kk][2] = bjv.z; acc[kk][3] = bjv.w;
        }
        for (int i = 0; i < C1; i += 4) {
            float4 w0 = *(const float4*)&W2[(i + 0) * C2 + j0];
            float4 w1 = *(const float4*)&W2[(i + 1) * C2 + j0];
            float4 w2 = *(const float4*)&W2[(i + 2) * C2 + j0];
            float4 w3 = *(const float4*)&W2[(i + 3) * C2 + j0];
#pragma unroll
            for (int kk = 0; kk < K / 4; ++kk) {
                float4 h = *(const float4*)&L.H[(k0 + kk) * C1 + i];  // bcast
                acc[kk][0] = fmaf(h.x, w0.x, acc[kk][0]);
                acc[kk][0] = fmaf(h.y, w1.x, acc[kk][0]);
                acc[kk][0] = fmaf(h.z, w2.x, acc[kk][0]);
                acc[kk][0] = fmaf(h.w, w3.x, acc[kk][0]);
                acc[kk][1] = fmaf(h.x, w0.y, acc[kk][1]);
                acc[kk][1] = fmaf(h.y, w1.y, acc[kk][1]);
                acc[kk][1] = fmaf(h.z, w2.y, acc[kk][1]);
                acc[kk][1] = fmaf(h.w, w3.y, acc[kk][1]);
                acc[kk][2] = fmaf(h.x, w0.z, acc[kk][2]);
                acc[kk][2] = fmaf(h.y, w1.z, acc[kk][2]);
                acc[kk][2] = fmaf(h.z, w2.z, acc[kk][2]);
                acc[kk][2] = fmaf(h.w, w3.z, acc[kk][2]);
                acc[kk][3] = fmaf(h.x, w0.w, acc[kk][3]);
                acc[kk][3] = fmaf(h.y, w1.w, acc[kk][3]);
                acc[kk][3] = fmaf(h.z, w2.w, acc[kk][3]);
                acc[kk][3] = fmaf(h.w, w3.w, acc[kk][3]);
            }
        }
        float m0 = NEGV, m1 = NEGV, m2 = NEGV, m3 = NEGV;
#pragma unroll
        for (int kk = 0; kk < K / 4; ++kk) {
            bool v = (k0 + kk < cntp) && (L.nd2s[k0 + kk] <= r2);
            if (v) {                            // wave-uniform branch
                m0 = fmaxf(m0, fmaxf(acc[kk][0], 0.f));
                m1 = fmaxf(m1, fmaxf(acc[kk][1], 0.f));
                m2 = fmaxf(m2, fmaxf(acc[kk][2], 0.f));
                m3 = fmaxf(m3, fmaxf(acc[kk][3], 0.f));
            }
        }
        float4 mv; mv.x = m0; mv.y = m1; mv.z = m2; mv.w = m3;
        *(float4*)&L.pm2[wv_][j0] = mv;
        __syncthreads();
        float r = fmaxf(fmaxf(L.pm2[0][t], L.pm2[1][t]),
                        fmaxf(L.pm2[2][t], L.pm2[3][t]));
        out[c * 384 + OUTOFF + t] = r;
    } else {
        // C2 == 128: 2 thread-groups split the k range, combine via LDS
        const int j2 = t % C2;
        const int g  = t / C2;
        float w2c[C1];
#pragma unroll
        for (int i = 0; i < C1; ++i) w2c[i] = W2[i * C2 + j2];
        const float bj = B2[j2];
        float omax = NEGV;
        for (int k = g; k < K; k += 2) {
            bool v = (k < cntp) && (L.nd2s[k] <= r2);
            if (!v) continue;
            float acc = bj;
            const float4* hr = (const float4*)&L.H[k * C1];
#pragma unroll
            for (int q = 0; q < C1 / 4; ++q) {
                float4 h = hr[q];
                acc = fmaf(h.x, w2c[4 * q + 0], acc);
                acc = fmaf(h.y, w2c[4 * q + 1], acc);
                acc = fmaf(h.z, w2c[4 * q + 2], acc);
                acc = fmaf(h.w, w2c[4 * q + 3], acc);
            }
            omax = fmaxf(omax, fmaxf(acc, 0.f));
        }
        L.pm[t] = omax;
        __syncthreads();
        if (t < C2) out[c * 384 + OUTOFF + t] = fmaxf(L.pm[t], L.pm[t + C2]);
    }
}

// ---------------------------------------------------------------------------
// Fused mega-kernel, 256 threads/block, batch-interleaved consumers.
// r16 (producer only): chunked publish BY T0 ONLY. r15's cross-wave publish
// (stores by waves 0-2, release by t0) FAILED (absmax 1.71 — consumers saw
// prog advance but stale pos_s): the release drain does not reliably cover
// other waves' plain stores. Every passing round (r7/8/10/11/13/14) had
// stores and release issued by THE SAME THREAD. r16 keeps that chain: t0
// buffers winner indices in LDS s_win[] (t0-written, t0-read) and every 64
// iters t0 alone writes the 64 ready centroids (192 scalar stores) then
// RELEASEs prog. The main loop now has ZERO global stores -> the per-iter
// barrier's implicit vmcnt(0) has nothing to drain (the suspected ~290
// cy/iter producer stall under consumer LLC load). Publish cost ~2000cy/64
// iters = ~31cy/iter amortized. If neutral: store-drain theory dead; gap is
// DVFS/fabric -> declare floor.
// ---------------------------------------------------------------------------
#define FPS_T   256
#define FPS_W   (FPS_T / 64)

#define REP32(X) X(0) X(1) X(2) X(3) X(4) X(5) X(6) X(7) \
                 X(8) X(9) X(10) X(11) X(12) X(13) X(14) X(15) \
                 X(16) X(17) X(18) X(19) X(20) X(21) X(22) X(23) \
                 X(24) X(25) X(26) X(27) X(28) X(29) X(30) X(31)

__global__ __launch_bounds__(256, 1) void mega_kernel(
        const float* __restrict__ x, const float* __restrict__ pos,
        const float* __restrict__ w1_0, const float* __restrict__ b1_0,
        const float* __restrict__ w1_1, const float* __restrict__ b1_1,
        const float* __restrict__ w2_0, const float* __restrict__ b2_0,
        const float* __restrict__ w2_1, const float* __restrict__ b2_1,
        float* __restrict__ out, float* pos_s, int* prog) {
    const int t = threadIdx.x;
    __shared__ MegaLds U;

    if (blockIdx.x < BATCH) {
        // =================== FPS producer ===================
        const int b = blockIdx.x;
        const float* pb = pos + b * NPTS * 3;
        const int w = t >> 6;               // wave 0..3
        const int lane = t & 63;

#define FPS_DECL(i) float px##i, py##i, pz##i, mind##i;
        REP32(FPS_DECL)
#undef FPS_DECL

#define FPS_LOAD(i) { int p = (i << 8) + t;                                   \
                      px##i = pb[3 * p + 0];                                  \
                      py##i = pb[3 * p + 1];                                  \
                      pz##i = pb[3 * p + 2];                                  \
                      float2 xy_; xy_.x = px##i; xy_.y = py##i;               \
                      U.f.sxy[p] = xy_;  U.f.sz[p] = pz##i;                   \
                      mind##i = 1e30f;                                        \
                      asm volatile("" : "+v"(px##i), "+v"(py##i), "+v"(pz##i)); }
        REP32(FPS_LOAD)
#undef FPS_LOAD
        if (t == 0) U.f.s_win[0] = 0;       // first centroid = point 0
        __syncthreads();

        float lx = U.f.sxy[0].x, ly = U.f.sxy[0].y, lz = U.f.sz[0];

        for (int m = 0; m < MCENT - 1; ++m) {
            // update mind (32 independent ops, full ILP)
#define FPS_UPD(i) { float d = dist2(px##i, py##i, pz##i, lx, ly, lz);        \
                     mind##i = fminf(mind##i, d); }
            REP32(FPS_UPD)
#undef FPS_UPD

            // tournament-tree argmax over 32 slots (strict >, left bias)
#define CMB(vo, io, va, ia, vb, ib)                                           \
            float vo; int io; { bool tk_ = (vb) > (va);                       \
                                vo = tk_ ? (vb) : (va);                       \
                                io = tk_ ? (ib) : (ia); }
            CMB(A0v,A0i,  mind0,0,   mind1,1)   CMB(A1v,A1i,  mind2,2,   mind3,3)
            CMB(A2v,A2i,  mind4,4,   mind5,5)   CMB(A3v,A3i,  mind6,6,   mind7,7)
            CMB(A4v,A4i,  mind8,8,   mind9,9)   CMB(A5v,A5i,  mind10,10, mind11,11)
            CMB(A6v,A6i,  mind12,12, mind13,13) CMB(A7v,A7i,  mind14,14, mind15,15)
            CMB(A8v,A8i,  mind16,16, mind17,17) CMB(A9v,A9i,  mind18,18, mind19,19)
            CMB(A10v,A10i,mind20,20, mind21,21) CMB(A11v,A11i,mind22,22, mind23,23)
            CMB(A12v,A12i,mind24,24, mind25,25) CMB(A13v,A13i,mind26,26, mind27,27)
            CMB(A14v,A14i,mind28,28, mind29,29) CMB(A15v,A15i,mind30,30, mind31,31)
            CMB(B0v,B0i, A0v,A0i,  A1v,A1i)   CMB(B1v,B1i, A2v,A2i,  A3v,A3i)
            CMB(B2v,B2i, A4v,A4i,  A5v,A5i)   CMB(B3v,B3i, A6v,A6i,  A7v,A7i)
            CMB(B4v,B4i, A8v,A8i,  A9v,A9i)   CMB(B5v,B5i, A10v,A10i,A11v,A11i)
            CMB(B6v,B6i, A12v,A12i,A13v,A13i) CMB(B7v,B7i, A14v,A14i,A15v,A15i)
            CMB(C0v,C0i, B0v,B0i, B1v,B1i)    CMB(C1v,C1i, B2v,B2i, B3v,B3i)
            CMB(C2v,C2i, B4v,B4i, B5v,B5i)    CMB(C3v,C3i, B6v,B6i, B7v,B7i)
            CMB(D0v,D0i, C0v,C0i, C1v,C1i)    CMB(D1v,D1i, C2v,C2i, C3v,C3i)
            CMB(E0v,E0i, D0v,D0i, D1v,D1i)
#undef CMB
            const float bv = E0v;
            const int   bp = (E0i << 8) + t;    // global point index

            // single u64 key chain: (d2 bits << 13) | (8191 - idx); 6
            // dependent KSTEPs absorb to lane 63 (value-monotone, inv-idx
            // tie -> min global index; r3-validated bit-exact).
            unsigned long long key =
                ((unsigned long long)__float_as_uint(bv) << 13) |
                (unsigned int)(8191 - bp);
            KSTEP(key, 0xB1)    // quad_perm xor1
            KSTEP(key, 0x4E)    // quad_perm xor2
            KSTEP(key, 0x141)   // row_half_mirror
            KSTEP(key, 0x140)   // row_mirror
            KSTEP(key, 0x142)   // row_bcast15
            KSTEP(key, 0x143)   // row_bcast31 -> lane63 holds wave winner

            const int par = m & 1;
            if (lane == 63) U.f.skey[par][w] = key;
            __syncthreads();

            // cross-wave: 4 slots, 2-step u64 butterfly (all-reduce)
            unsigned long long k = U.f.skey[par][t & 3];
            KSTEP(k, 0xB1)
            KSTEP(k, 0x4E)

            int gp = 8191 - (int)(k & 0x1FFFULL);
            if (t == 0) {
                U.f.s_win[m + 1] = gp;          // LDS only (t0-private use)
                // chunked publish by t0 ONLY (same-thread store+release —
                // the 6x-validated visibility chain)
                if ((m & 63) == 63) {
                    float* o = pos_s + (b * MCENT + (m - 63)) * 3;
                    for (int q = 0; q < 64; ++q) {
                        int gq = U.f.s_win[m - 63 + q];
                        float2 xy = U.f.sxy[gq];
                        float  z  = U.f.sz[gq];
                        o[3 * q + 0] = xy.x;
                        o[3 * q + 1] = xy.y;
                        o[3 * q + 2] = z;
                    }
                    __hip_atomic_store(&prog[b * PROG_STRIDE], m + 1,
                                       __ATOMIC_RELEASE,
                                       __HIP_MEMORY_SCOPE_AGENT);
                }
            }
            float2 cxy = U.f.sxy[gp];           // broadcast LDS read
            lx = cxy.x; ly = cxy.y; lz = U.f.sz[gp];
        }

        // epilogue: t0 publishes the final 64 centroids (1984..2047)
        if (t == 0) {
            float* o = pos_s + (b * MCENT + (MCENT - 64)) * 3;
            for (int q = 0; q < 64; ++q) {
                int gq = U.f.s_win[MCENT - 64 + q];
                float2 xy = U.f.sxy[gq];
                float  z  = U.f.sz[gq];
                o[3 * q + 0] = xy.x;
                o[3 * q + 1] = xy.y;
                o[3 * q + 2] = z;
            }
            __hip_atomic_store(&prog[b * PROG_STRIDE], MCENT,
                               __ATOMIC_RELEASE, __HIP_MEMORY_SCOPE_AGENT);
        }
        return;
    }

    // =================== per-centroid consumer (batch-interleaved) =========
    const int idx = blockIdx.x - BATCH;
    const int b   = idx & 3;            // batches alternate in dispatch order
    const int m   = idx >> 2;
    const int c   = b * MCENT + m;
    KnnLds& L = U.k;
    const float* pb = pos + b * NPTS * 3;

    if (t < KMAX) { L.nbr[t] = 0; L.nd2s[t] = 1e30f; L.hist[t] = 0; }
    if (t == 0) L.cnt2 = 0;

    if (t == 0) {
        int tries = 0;
        while (__hip_atomic_load(&prog[b * PROG_STRIDE], __ATOMIC_RELAXED,
                                 __HIP_MEMORY_SCOPE_AGENT) < m + 1) {
            __builtin_amdgcn_s_sleep(32);
            if (++tries >= (1 << 18)) break;    // pathology -> visible fail
        }
        asm volatile("" ::: "memory");
        // centroid coords via LLC atomic loads (released by producer)
        L.ctr[0] = __hip_atomic_load(&pos_s[c * 3 + 0], __ATOMIC_RELAXED,
                                     __HIP_MEMORY_SCOPE_AGENT);
        L.ctr[1] = __hip_atomic_load(&pos_s[c * 3 + 1], __ATOMIC_RELAXED,
                                     __HIP_MEMORY_SCOPE_AGENT);
        L.ctr[2] = __hip_atomic_load(&pos_s[c * 3 + 2], __ATOMIC_RELAXED,
                                     __HIP_MEMORY_SCOPE_AGENT);
    }
    __syncthreads();
    const float cx = L.ctr[0], cy = L.ctr[1], cz = L.ctr[2];

    // ---- knn: histogram radix-select + exact rank (r6 256t) ----
    float d2r[32];
#pragma unroll
    for (int i = 0; i < 32; ++i) {
        int p = (i << 8) + t;
        float d2 = dist2(cx, cy, cz, pb[3 * p + 0], pb[3 * p + 1], pb[3 * p + 2]);
        d2r[i] = d2;
        if (d2 <= 0.16f) {
            int bkt = (int)(d2 * 400.0f);      // monotone; 0.16f*400 < 64
            bkt = bkt > 63 ? 63 : bkt;
            atomicAdd(&L.hist[bkt], 1);
        }
    }
    __syncthreads();
    if (t == 0) {
        int cum = 0, B = -1;
#pragma unroll
        for (int j = 0; j < 64; ++j) {
            cum += L.hist[j];
            if (B < 0 && cum >= 64) B = j;
        }
        L.B64 = (B < 0) ? 63 : B;
        L.total = cum;
    }
    __syncthreads();
    const int B64 = L.B64;
#pragma unroll
    for (int i = 0; i < 32; ++i) {
        float d2 = d2r[i];
        if (d2 <= 0.16f) {
            int bkt = (int)(d2 * 400.0f);
            bkt = bkt > 63 ? 63 : bkt;
            if (bkt <= B64) {
                int slot = atomicAdd(&L.cnt2, 1);
                if (slot < KNN_CAP) {
                    int p = (i << 8) + t;
                    L.cand[slot] =
                        ((unsigned long long)__float_as_uint(d2) << 32) |
                        (unsigned int)p;
                }
            }
        }
    }
    __syncthreads();
    const int C = L.cnt2 < KNN_CAP ? L.cnt2 : KNN_CAP;
    for (int tc = t; tc < C; tc += 256) {
        unsigned long long my = L.cand[tc];
        int rank = 0;
        for (int j = 0; j < C; ++j) rank += (L.cand[j] < my) ? 1 : 0;
        if (rank < KMAX) {
            L.nbr[rank]  = (int)(my & 0xffffffffULL);
            L.nd2s[rank] = __uint_as_float((unsigned int)(my >> 32));
        }
    }
    if (t == 0) L.cntk = L.total < KMAX ? L.total : KMAX;
    __syncthreads();
    if (t < KMAX) {
        const float* pp = pos + (b * NPTS + L.nbr[t]) * 3;
        float4 p;
        p.x = pp[0] - cx; p.y = pp[1] - cy; p.z = pp[2] - cz; p.w = 0.f;
        L.p3[t] = p;
    }
    __syncthreads();

    mlp_phase<32, 64, 128, 0>(L, x, w1_0, b1_0, w1_1, b1_1, out, 0.04f, c, b, t);
    __syncthreads();
    mlp_phase<64, 128, 256, 128>(L, x, w2_0, b2_0, w2_1, b2_1, out, 0.16f, c, b, t);
}
#undef KSTEP

extern "C" void kernel_launch(void* const* d_in, const int* in_sizes, int n_in,
                              void* d_out, int out_size, void* d_ws, size_t ws_size,
                              hipStream_t stream) {
    const float* x    = (const float*)d_in[0];
    const float* pos  = (const float*)d_in[1];
    const float* w1_0 = (const float*)d_in[2];
    const float* b1_0 = (const float*)d_in[3];
    const float* w1_1 = (const float*)d_in[4];
    const float* b1_1 = (const float*)d_in[5];
    const float* w2_0 = (const float*)d_in[6];
    const float* b2_0 = (const float*)d_in[7];
    const float* w2_1 = (const float*)d_in[8];
    const float* b2_1 = (const float*)d_in[9];

    float* out   = (float*)d_out;
    float* pos_s = out + NCENT * 384;          // second output

    int* prog = (int*)d_ws;                    // 4 counters, 128B apart

    hipMemsetAsync(prog, 0, BATCH * PROG_STRIDE * sizeof(int), stream);
    mega_kernel<<<BATCH + NCENT, 256, 0, stream>>>(
        x, pos, w1_0, b1_0, w1_1, b1_1, w2_0, b2_0, w2_1, b2_1,
        out, pos_s, prog);
}

// Round 17
// 2065.393 us; speedup vs baseline: 1.0559x; 1.0488x over previous
//
#include <hip/hip_runtime.h>
#include <stdint.h>

#define BATCH 4
#define NPTS  8192
#define CFEAT 64
#define MCENT 2048
#define NCENT (BATCH * MCENT)
#define KMAX  64
#define NEGV  -1e30f
#define KNN_CAP 320
#define PROG_STRIDE 32   // ints; one 128B cache line per batch counter

// Exact-rounding squared distance, matching numpy's ((dx*dx+dy*dy)+dz*dz)
// with NO fma contraction (discrete neighbor selection requires bit parity).
__device__ __forceinline__ float dist2(float ax, float ay, float az,
                                       float bx, float by, float bz) {
    float dx = __fsub_rn(ax, bx);
    float dy = __fsub_rn(ay, by);
    float dz = __fsub_rn(az, bz);
    return __fadd_rn(__fadd_rn(__fmul_rn(dx, dx), __fmul_rn(dy, dy)),
                     __fmul_rn(dz, dz));
}

template <int CTRL>
__device__ __forceinline__ int dppi(int v) {
    return __builtin_amdgcn_update_dpp(v, v, CTRL, 0xF, 0xF, false);
}

// u64 max-combine with a DPP lane permute (lo/hi words permuted separately).
#define KSTEP(k, C_) { int klo_ = dppi<C_>((int)(unsigned int)(k));           \
                       int khi_ = dppi<C_>((int)(unsigned int)((k) >> 32));   \
                       unsigned long long ok_ =                               \
                           ((unsigned long long)(unsigned int)khi_ << 32) |   \
                           (unsigned int)klo_;                                \
                       (k) = ok_ > (k) ? ok_ : (k); }

// ---------------------------------------------------------------------------
// LDS union. 104.1 KB -> 1 block/CU at 512 threads (8 waves, 2 waves/SIMD;
// VGPR cap 128 — consumer path register demand trimmed below it, see mlp).
// ---------------------------------------------------------------------------
struct FpsLds {
    float2 sxy[NPTS];                    // 64 KB
    float  sz[NPTS];                     // 32 KB
    int    s_win[MCENT];                 // 8 KB winner indices (t0-only)
    unsigned long long skey[2][8];
};
struct KnnLds {
    float4 p3[KMAX];                     // pos[nbr]-ctr (w=0)
    float  H[KMAX * 128];                // 32 KB hidden activations
    unsigned long long cand[KNN_CAP];    // 2.5 KB
    float  pm2[4][256];                  // 4 KB  (C2==256 combine)
    float  pm[256];                      // 1 KB  (C2==128 combine)
    int    hist[64];
    int    nbr[KMAX];
    float  nd2s[KMAX];
    float  ctr[4];
    int    B64, total, cnt2, cntk;
};
union MegaLds { FpsLds f; KnnLds k; };

// ---------------------------------------------------------------------------
// Per-centroid MLP phase. Block is 512t; COMPUTE RUNS ON t<256 ONLY (act
// guard) so per-thread register demand stays under the 512t 128-VGPR cap:
//  - L1/L2 tiling identical to the r16 256t version (bit-exact fma order)
//  - C2==256: the acc[16][4]=64-reg k-split is cut to TWO PASSES of
//    acc[8][4] (chunked k; W2 re-read; masked-max keeps ascending-k order,
//    fmax exactly associative -> bit-identical result)
// All __syncthreads are unconditional (executed by all 512 threads).
// ---------------------------------------------------------------------------
template <int K, int C1, int C2, int OUTOFF>
__device__ __forceinline__ void mlp_phase(
        KnnLds& L, const float* __restrict__ x,
        const float* __restrict__ W1, const float* __restrict__ B1,
        const float* __restrict__ W2, const float* __restrict__ B2,
        float* __restrict__ out, float r2, int c, int b, int t) {
    constexpr int HK  = K / 8;      // k-rows per half-wave (8 half-waves)
    constexpr int NJ1 = C1 / 32;    // j-cols per lane (4 or 2)
    const bool act = t < 256;
    if (act) {
        const int hw = t >> 5;          // half-wave 0..7
        const int sl = t & 31;
        const int k0 = hw * HK;
        const int j0 = sl * NJ1;

        int xo[HK];
#pragma unroll
        for (int kk = 0; kk < HK; ++kk)
            xo[kk] = (b * NPTS + L.nbr[k0 + kk]) * CFEAT;

        float acc[HK][NJ1];
#pragma unroll
        for (int kk = 0; kk < HK; ++kk)
#pragma unroll
            for (int j = 0; j < NJ1; ++j) acc[kk][j] = B1[j0 + j];

#pragma unroll 4
        for (int q = 0; q < 16; ++q) {  // x rows 4q..4q+3
            float wr[4][NJ1];
#pragma unroll
            for (int r = 0; r < 4; ++r)
#pragma unroll
                for (int j = 0; j < NJ1; ++j)
                    wr[r][j] = W1[(4 * q + r) * C1 + j0 + j];
#pragma unroll
            for (int kk = 0; kk < HK; ++kk) {
                float4 h = *(const float4*)(x + xo[kk] + 4 * q);
#pragma unroll
                for (int j = 0; j < NJ1; ++j) {
                    float a = acc[kk][j];
                    a = fmaf(h.x, wr[0][j], a);
                    a = fmaf(h.y, wr[1][j], a);
                    a = fmaf(h.z, wr[2][j], a);
                    a = fmaf(h.w, wr[3][j], a);
                    acc[kk][j] = a;
                }
            }
        }
        {   // tail: rows 64,65,66 (pos-delta) + zero row 67
            float wr[4][NJ1];
#pragma unroll
            for (int r = 0; r < 3; ++r)
#pragma unroll
                for (int j = 0; j < NJ1; ++j)
                    wr[r][j] = W1[(64 + r) * C1 + j0 + j];
#pragma unroll
            for (int j = 0; j < NJ1; ++j) wr[3][j] = 0.f;
#pragma unroll
            for (int kk = 0; kk < HK; ++kk) {
                float4 h = L.p3[k0 + kk];       // h.w == 0
#pragma unroll
                for (int j = 0; j < NJ1; ++j) {
                    float a = acc[kk][j];
                    a = fmaf(h.x, wr[0][j], a);
                    a = fmaf(h.y, wr[1][j], a);
                    a = fmaf(h.z, wr[2][j], a);
                    a = fmaf(h.w, wr[3][j], a);
                    acc[kk][j] = a;
                }
            }
        }
#pragma unroll
        for (int kk = 0; kk < HK; ++kk) {
            if constexpr (NJ1 == 4) {
                float4 o;
                o.x = fmaxf(acc[kk][0], 0.f); o.y = fmaxf(acc[kk][1], 0.f);
                o.z = fmaxf(acc[kk][2], 0.f); o.w = fmaxf(acc[kk][3], 0.f);
                *(float4*)&L.H[(k0 + kk) * C1 + j0] = o;
            } else {
                float2 o;
                o.x = fmaxf(acc[kk][0], 0.f); o.y = fmaxf(acc[kk][1], 0.f);
                *(float2*)&L.H[(k0 + kk) * C1 + j0] = o;
            }
        }
    }
    __syncthreads();

    const int cntk = L.cntk;
    const int cntp = cntk < K ? cntk : K;

    if constexpr (C2 == 256) {
        if (act) {
            // k-split across 4 waves; TWO passes of 8 k-rows (acc[8][4]).
            const int lane_ = t & 63;
            const int wv_   = t >> 6;           // 0..3
            const int j0    = lane_ * 4;
            float4 bjv = *(const float4*)&B2[j0];
            float mx0 = NEGV, mx1 = NEGV, mx2 = NEGV, mx3 = NEGV;
#pragma unroll
            for (int ch = 0; ch < 2; ++ch) {
                const int k0 = wv_ * (K / 4) + ch * 8;
                float acc[8][4];
#pragma unroll
                for (int kk = 0; kk < 8; ++kk) {
                    acc[kk][0] = bjv.x; acc[kk][1] = bjv.y;
                    acc[kk][2] = bjv.z; acc[kk][3] = bjv.w;
                }
                for (int i = 0; i < C1; i += 4) {
                    float4 w0 = *(const float4*)&W2[(i + 0) * C2 + j0];
                    float4 w1 = *(const float4*)&W2[(i + 1) * C2 + j0];
                    float4 w2 = *(const float4*)&W2[(i + 2) * C2 + j0];
                    float4 w3 = *(const float4*)&W2[(i + 3) * C2 + j0];
#pragma unroll
                    for (int kk = 0; kk < 8; ++kk) {
                        float4 h = *(const float4*)&L.H[(k0 + kk) * C1 + i];
                        acc[kk][0] = fmaf(h.x, w0.x, acc[kk][0]);
                        acc[kk][0] = fmaf(h.y, w1.x, acc[kk][0]);
                        acc[kk][0] = fmaf(h.z, w2.x, acc[kk][0]);
                        acc[kk][0] = fmaf(h.w, w3.x, acc[kk][0]);
                        acc[kk][1] = fmaf(h.x, w0.y, acc[kk][1]);
                        acc[kk][1] = fmaf(h.y, w1.y, acc[kk][1]);
                        acc[kk][1] = fmaf(h.z, w2.y, acc[kk][1]);
                        acc[kk][1] = fmaf(h.w, w3.y, acc[kk][1]);
                        acc[kk][2] = fmaf(h.x, w0.z, acc[kk][2]);
                        acc[kk][2] = fmaf(h.y, w1.z, acc[kk][2]);
                        acc[kk][2] = fmaf(h.z, w2.z, acc[kk][2]);
                        acc[kk][2] = fmaf(h.w, w3.z, acc[kk][2]);
                        acc[kk][3] = fmaf(h.x, w0.w, acc[kk][3]);
                        acc[kk][3] = fmaf(h.y, w1.w, acc[kk][3]);
                        acc[kk][3] = fmaf(h.z, w2.w, acc[kk][3]);
                        acc[kk][3] = fmaf(h.w, w3.w, acc[kk][3]);
                    }
                }
#pragma unroll
                for (int kk = 0; kk < 8; ++kk) {
                    bool v = (k0 + kk < cntp) && (L.nd2s[k0 + kk] <= r2);
                    if (v) {                    // wave-uniform branch
                        mx0 = fmaxf(mx0, fmaxf(acc[kk][0], 0.f));
                        mx1 = fmaxf(mx1, fmaxf(acc[kk][1], 0.f));
                        mx2 = fmaxf(mx2, fmaxf(acc[kk][2], 0.f));
                        mx3 = fmaxf(mx3, fmaxf(acc[kk][3], 0.f));
                    }
                }
            }
            float4 mv; mv.x = mx0; mv.y = mx1; mv.z = mx2; mv.w = mx3;
            *(float4*)&L.pm2[wv_][j0] = mv;
        }
        __syncthreads();
        if (t < C2) {
            float r = fmaxf(fmaxf(L.pm2[0][t], L.pm2[1][t]),
                            fmaxf(L.pm2[2][t], L.pm2[3][t]));
            out[c * 384 + OUTOFF + t] = r;
        }
    } else {
        if (act) {
            // C2 == 128: 2 thread-groups split the k range, combine via LDS
            const int j2 = t % C2;
            const int g  = t / C2;
            float w2c[C1];
#pragma unroll
            for (int i = 0; i < C1; ++i) w2c[i] = W2[i * C2 + j2];
            const float bj = B2[j2];
            float omax = NEGV;
            for (int k = g; k < K; k += 2) {
                bool v = (k < cntp) && (L.nd2s[k] <= r2);
                if (!v) continue;
                float acc = bj;
                const float4* hr = (const float4*)&L.H[k * C1];
#pragma unroll
                for (int q = 0; q < C1 / 4; ++q) {
                    float4 h = hr[q];
                    acc = fmaf(h.x, w2c[4 * q + 0], acc);
                    acc = fmaf(h.y, w2c[4 * q + 1], acc);
                    acc = fmaf(h.z, w2c[4 * q + 2], acc);
                    acc = fmaf(h.w, w2c[4 * q + 3], acc);
                }
                omax = fmaxf(omax, fmaxf(acc, 0.f));
            }
            L.pm[t] = omax;
        }
        __syncthreads();
        if (t < C2) out[c * 384 + OUTOFF + t] = fmaxf(L.pm[t], L.pm[t + C2]);
    }
}

// ---------------------------------------------------------------------------
// Fused mega-kernel, 512 threads/block, batch-interleaved consumers.
// r17: producer restored to the 512t r3 configuration (measured 1822us
// standalone vs 2004 at 256t — 2 waves/SIMD hides the VALU latency) with
// r16's validated t0-only chunk publish. Consumers: knn at full 512t
// (r7/r8-validated indexing, d2r[16]); mlp compute on t<256 with the
// register-heavy C2==256 k-split cut to two acc[8][4] passes, keeping
// kernel demand under the 512t 128-VGPR cap. Spill tripwire: if WRITE_SIZE
// explodes (r7's 2.67GB signature), revert to r16.
// ---------------------------------------------------------------------------
#define FPS_T   512
#define FPS_W   (FPS_T / 64)

#define REP16(X) X(0) X(1) X(2) X(3) X(4) X(5) X(6) X(7) \
                 X(8) X(9) X(10) X(11) X(12) X(13) X(14) X(15)

__global__ __launch_bounds__(FPS_T, 2) void mega_kernel(
        const float* __restrict__ x, const float* __restrict__ pos,
        const float* __restrict__ w1_0, const float* __restrict__ b1_0,
        const float* __restrict__ w1_1, const float* __restrict__ b1_1,
        const float* __restrict__ w2_0, const float* __restrict__ b2_0,
        const float* __restrict__ w2_1, const float* __restrict__ b2_1,
        float* __restrict__ out, float* pos_s, int* prog) {
    const int t = threadIdx.x;
    __shared__ MegaLds U;

    if (blockIdx.x < BATCH) {
        // =================== FPS producer (r3 512t verbatim + publish) =====
        const int b = blockIdx.x;
        const float* pb = pos + b * NPTS * 3;
        const int w = t >> 6;               // wave 0..7
        const int lane = t & 63;

#define FPS_DECL(i) float px##i, py##i, pz##i, mind##i;
        REP16(FPS_DECL)
#undef FPS_DECL

#define FPS_LOAD(i) { int p = (i << 9) + t;                                   \
                      px##i = pb[3 * p + 0];                                  \
                      py##i = pb[3 * p + 1];                                  \
                      pz##i = pb[3 * p + 2];                                  \
                      float2 xy_; xy_.x = px##i; xy_.y = py##i;               \
                      U.f.sxy[p] = xy_;  U.f.sz[p] = pz##i;                   \
                      mind##i = 1e30f;                                        \
                      asm volatile("" : "+v"(px##i), "+v"(py##i), "+v"(pz##i)); }
        REP16(FPS_LOAD)
#undef FPS_LOAD
        if (t == 0) U.f.s_win[0] = 0;       // first centroid = point 0
        __syncthreads();

        float lx = U.f.sxy[0].x, ly = U.f.sxy[0].y, lz = U.f.sz[0];

        for (int m = 0; m < MCENT - 1; ++m) {
            // update mind + thread-local argmax (i ascending == point index
            // ascending for fixed t; strict > keeps lowest index)
            float bv = -1.0f; int bi = 0;
#define FPS_UPD(i) { float d = dist2(px##i, py##i, pz##i, lx, ly, lz);        \
                     float mn = fminf(mind##i, d);                            \
                     mind##i = mn;                                            \
                     bool tk = mn > bv;                                       \
                     bv = tk ? mn : bv;                                       \
                     bi = tk ? i : bi; }
            REP16(FPS_UPD)
#undef FPS_UPD
            int bp = (bi << 9) + t;

            // u64 key: (d2 bits << 13) | (8191 - idx); absorb to lane 63
            unsigned long long key =
                ((unsigned long long)__float_as_uint(bv) << 13) |
                (unsigned int)(8191 - bp);
            KSTEP(key, 0xB1)    // quad_perm xor1
            KSTEP(key, 0x4E)    // quad_perm xor2
            KSTEP(key, 0x141)   // row_half_mirror
            KSTEP(key, 0x140)   // row_mirror
            KSTEP(key, 0x142)   // row_bcast15
            KSTEP(key, 0x143)   // row_bcast31 -> lane63 holds wave winner

            const int par = m & 1;
            if (lane == 63) U.f.skey[par][w] = key;
            __syncthreads();

            // cross-wave: 8 slots, 3-step u64 butterfly (all-reduce)
            unsigned long long k = U.f.skey[par][t & 7];
            KSTEP(k, 0xB1)
            KSTEP(k, 0x4E)
            KSTEP(k, 0x141)

            int gp = 8191 - (int)(k & 0x1FFFULL);
            if (t == 0) {
                U.f.s_win[m + 1] = gp;          // LDS, t0-private use
                // chunked publish by t0 ONLY (same-thread store+release —
                // the validated visibility chain; r15's cross-wave variant
                // FAILED, never reintroduce)
                if ((m & 63) == 63) {
                    float* o = pos_s + (b * MCENT + (m - 63)) * 3;
                    for (int q = 0; q < 64; ++q) {
                        int gq = U.f.s_win[m - 63 + q];
                        float2 xy = U.f.sxy[gq];
                        float  z  = U.f.sz[gq];
                        o[3 * q + 0] = xy.x;
                        o[3 * q + 1] = xy.y;
                        o[3 * q + 2] = z;
                    }
                    __hip_atomic_store(&prog[b * PROG_STRIDE], m + 1,
                                       __ATOMIC_RELEASE,
                                       __HIP_MEMORY_SCOPE_AGENT);
                }
            }
            float2 cxy = U.f.sxy[gp];           // broadcast LDS read
            lx = cxy.x; ly = cxy.y; lz = U.f.sz[gp];
        }

        // epilogue: t0 publishes the final 64 centroids (1984..2047)
        if (t == 0) {
            float* o = pos_s + (b * MCENT + (MCENT - 64)) * 3;
            for (int q = 0; q < 64; ++q) {
                int gq = U.f.s_win[MCENT - 64 + q];
                float2 xy = U.f.sxy[gq];
                float  z  = U.f.sz[gq];
                o[3 * q + 0] = xy.x;
                o[3 * q + 1] = xy.y;
                o[3 * q + 2] = z;
            }
            __hip_atomic_store(&prog[b * PROG_STRIDE], MCENT,
                               __ATOMIC_RELEASE, __HIP_MEMORY_SCOPE_AGENT);
        }
        return;
    }

    // =================== per-centroid consumer (batch-interleaved) =========
    const int idx = blockIdx.x - BATCH;
    const int b   = idx & 3;            // batches alternate in dispatch order
    const int m   = idx >> 2;
    const int c   = b * MCENT + m;
    KnnLds& L = U.k;
    const float* pb = pos + b * NPTS * 3;

    if (t < KMAX) { L.nbr[t] = 0; L.nd2s[t] = 1e30f; L.hist[t] = 0; }
    if (t == 0) L.cnt2 = 0;

    if (t == 0) {
        int tries = 0;
        while (__hip_atomic_load(&prog[b * PROG_STRIDE], __ATOMIC_RELAXED,
                                 __HIP_MEMORY_SCOPE_AGENT) < m + 1) {
            __builtin_amdgcn_s_sleep(32);
            if (++tries >= (1 << 18)) break;    // pathology -> visible fail
        }
        asm volatile("" ::: "memory");
        // centroid coords via LLC atomic loads (released by producer)
        L.ctr[0] = __hip_atomic_load(&pos_s[c * 3 + 0], __ATOMIC_RELAXED,
                                     __HIP_MEMORY_SCOPE_AGENT);
        L.ctr[1] = __hip_atomic_load(&pos_s[c * 3 + 1], __ATOMIC_RELAXED,
                                     __HIP_MEMORY_SCOPE_AGENT);
        L.ctr[2] = __hip_atomic_load(&pos_s[c * 3 + 2], __ATOMIC_RELAXED,
                                     __HIP_MEMORY_SCOPE_AGENT);
    }
    __syncthreads();
    const float cx = L.ctr[0], cy = L.ctr[1], cz = L.ctr[2];

    // ---- knn at full 512t (r7/r8-validated): histogram radix-select ----
    float d2r[16];
#pragma unroll
    for (int i = 0; i < 16; ++i) {
        int p = (i << 9) + t;
        float d2 = dist2(cx, cy, cz, pb[3 * p + 0], pb[3 * p + 1], pb[3 * p + 2]);
        d2r[i] = d2;
        if (d2 <= 0.16f) {
            int bkt = (int)(d2 * 400.0f);      // monotone; 0.16f*400 < 64
            bkt = bkt > 63 ? 63 : bkt;
            atomicAdd(&L.hist[bkt], 1);
        }
    }
    __syncthreads();
    if (t == 0) {
        int cum = 0, B = -1;
#pragma unroll
        for (int j = 0; j < 64; ++j) {
            cum += L.hist[j];
            if (B < 0 && cum >= 64) B = j;
        }
        L.B64 = (B < 0) ? 63 : B;
        L.total = cum;
    }
    __syncthreads();
    const int B64 = L.B64;
#pragma unroll
    for (int i = 0; i < 16; ++i) {
        float d2 = d2r[i];
        if (d2 <= 0.16f) {
            int bkt = (int)(d2 * 400.0f);
            bkt = bkt > 63 ? 63 : bkt;
            if (bkt <= B64) {
                int slot = atomicAdd(&L.cnt2, 1);
                if (slot < KNN_CAP) {
                    int p = (i << 9) + t;
                    L.cand[slot] =
                        ((unsigned long long)__float_as_uint(d2) << 32) |
                        (unsigned int)p;
                }
            }
        }
    }
    __syncthreads();
    const int C = L.cnt2 < KNN_CAP ? L.cnt2 : KNN_CAP;
    for (int tc = t; tc < C; tc += 512) {
        unsigned long long my = L.cand[tc];
        int rank = 0;
        for (int j = 0; j < C; ++j) rank += (L.cand[j] < my) ? 1 : 0;
        if (rank < KMAX) {
            L.nbr[rank]  = (int)(my & 0xffffffffULL);
            L.nd2s[rank] = __uint_as_float((unsigned int)(my >> 32));
        }
    }
    if (t == 0) L.cntk = L.total < KMAX ? L.total : KMAX;
    __syncthreads();
    if (t < KMAX) {
        const float* pp = pos + (b * NPTS + L.nbr[t]) * 3;
        float4 p;
        p.x = pp[0] - cx; p.y = pp[1] - cy; p.z = pp[2] - cz; p.w = 0.f;
        L.p3[t] = p;
    }
    __syncthreads();

    mlp_phase<32, 64, 128, 0>(L, x, w1_0, b1_0, w1_1, b1_1, out, 0.04f, c, b, t);
    __syncthreads();
    mlp_phase<64, 128, 256, 128>(L, x, w2_0, b2_0, w2_1, b2_1, out, 0.16f, c, b, t);
}
#undef KSTEP

extern "C" void kernel_launch(void* const* d_in, const int* in_sizes, int n_in,
                              void* d_out, int out_size, void* d_ws, size_t ws_size,
                              hipStream_t stream) {
    const float* x    = (const float*)d_in[0];
    const float* pos  = (const float*)d_in[1];
    const float* w1_0 = (const float*)d_in[2];
    const float* b1_0 = (const float*)d_in[3];
    const float* w1_1 = (const float*)d_in[4];
    const float* b1_1 = (const float*)d_in[5];
    const float* w2_0 = (const float*)d_in[6];
    const float* b2_0 = (const float*)d_in[7];
    const float* w2_1 = (const float*)d_in[8];
    const float* b2_1 = (const float*)d_in[9];

    float* out   = (float*)d_out;
    float* pos_s = out + NCENT * 384;          // second output

    int* prog = (int*)d_ws;                    // 4 counters, 128B apart

    hipMemsetAsync(prog, 0, BATCH * PROG_STRIDE * sizeof(int), stream);
    mega_kernel<<<BATCH + NCENT, FPS_T, 0, stream>>>(
        x, pos, w1_0, b1_0, w1_1, b1_1, w2_0, b2_0, w2_1, b2_1,
        out, pos_s, prog);
}